// Round 18
// baseline (88.193 us; speedup 1.0000x reference)
//
#include <hip/hip_runtime.h>
#include <hip/hip_bf16.h>

#define BB 4096
#define NNB 20
#define GG 4
#define DIN 128
#define EE 64
#define HH 8

typedef short bf16x8 __attribute__((ext_vector_type(8)));
typedef float f32x4 __attribute__((ext_vector_type(4)));

__device__ __forceinline__ float lrelu_f(float x) { return x > 0.f ? x : 0.2f * x; }
__device__ __forceinline__ unsigned short f2bf(float f) {
  unsigned u = __float_as_uint(f);
  return (unsigned short)((u + 0x7fffu + ((u >> 16) & 1u)) >> 16);
}
__device__ __forceinline__ float bf2f(unsigned short s) {
  return __uint_as_float(((unsigned)s) << 16);
}

// ---------------- K0: prep (unchanged, cold) ----------------
__global__ __launch_bounds__(256) void prep_kernel(
    const float* __restrict__ W_heads, const float* __restrict__ a_self,
    const float* __restrict__ a_neigh, const float* __restrict__ W_out,
    unsigned short* __restrict__ P1Whi, unsigned short* __restrict__ P1Wlo,
    unsigned short* __restrict__ WBhi, unsigned short* __restrict__ WBlo,
    unsigned short* __restrict__ WOhi, unsigned short* __restrict__ WOlo) {
  int id = blockIdx.x * 256 + threadIdx.x;
  if (id < 2048) {
    int j = id & 7, lane = (id >> 3) & 63, kb = id >> 9;
    int col = lane & 15, k = kb * 32 + (lane >> 4) * 8 + j;
    int h = col & 7;
    const float* a = (col < 8) ? a_neigh : a_self;
    const float* Wrow = W_heads + (h * DIN + k) * EE;
    float acc = 0.f;
    for (int e = 0; e < EE; ++e) acc = fmaf(Wrow[e], a[h * EE + e], acc);
    unsigned short hi = f2bf(acc);
    P1Whi[id] = hi;
    P1Wlo[id] = f2bf(acc - bf2f(hi));
  } else if (id < 2048 + 65536) {
    int rel = id - 2048;   // (((h*4+nt)*4+kb)*64 + l)*8 + j
    int j = rel & 7, l = (rel >> 3) & 63, kb = (rel >> 9) & 3, nt = (rel >> 11) & 3, h = rel >> 13;
    int d = kb * 32 + (l >> 4) * 8 + j;
    int e = nt * 16 + (l & 15);
    float w = W_heads[(h * DIN + d) * EE + e];
    unsigned short hi = f2bf(w);
    WBhi[rel] = hi;
    WBlo[rel] = f2bf(w - bf2f(hi));
  } else if (id < 2048 + 65536 + 32768) {
    int rel = id - 2048 - 65536;  // ((nt*16+kb)*64 + l)*8 + j
    int j = rel & 7, l = (rel >> 3) & 63, kb = (rel >> 9) & 15, nt = rel >> 13;
    int k = kb * 32 + (l >> 4) * 8 + j;
    int n = nt * 16 + (l & 15);
    float w = W_out[k * EE + n];
    unsigned short hi = f2bf(w);
    WOhi[rel] = hi;
    WOlo[rel] = f2bf(w - bf2f(hi));
  }
}

// ---------------- Fused kernel: 256 threads (4 waves), 2 b's = 8 bg rows ----------------
// 2048 blocks; LDS 24,576 B -> up to 6 blocks/CU (24 waves) for cross-block
// phase overlap (R9-R17 plateaued at 2 blocks/CU, phases serialized).
// MFMA M=16 tiles carry rows 8-15 as mirrors of 0-7 (valid-row guards kg<2).
// LDS:
//   [0,16384):     P1: wf staging [0,8192). P3+: agg bf16 [bg8][h8][d128],
//                  byte ^ (bg<<4).
//   [16384,24576): P1-P3: att f32 [n20][bg8][h8] (5,120 B used).
//                  B-C: h bf16 [row8][k512], byte ^ (row<<4).
__global__ __launch_bounds__(256, 4) void fused_kernel(
    const float* __restrict__ self_vecs, const float* __restrict__ neigh_vecs,
    const unsigned short* __restrict__ P1Whi, const unsigned short* __restrict__ P1Wlo,
    const unsigned short* __restrict__ WBhi, const unsigned short* __restrict__ WBlo,
    const unsigned short* __restrict__ WOhi, const unsigned short* __restrict__ WOlo,
    float* __restrict__ out) {
  __shared__ char smem[24576];
  char* aggb = smem;
  float* attw = (float*)(smem + 16384);
  char* hb = smem + 16384;

  const int t = threadIdx.x;
  const int w = t >> 6, lane = t & 63;
  const int m = lane & 15, kg = lane >> 4;
  const int m8 = m & 7;                    // valid row (rows 8-15 mirror 0-7)
  const int bid = blockIdx.x;

#define LOAD_X(X, ptr)                                                         \
  {                                                                            \
    const float4* p_ = (const float4*)(ptr);                                   \
    _Pragma("unroll") for (int q = 0; q < 4; ++q) {                            \
      X[2 * q]     = p_[q * 8 + kg * 2];                                       \
      X[2 * q + 1] = p_[q * 8 + kg * 2 + 1];                                   \
    }                                                                          \
  }

  // hi-only A convert + 8 MFMA; wf from LDS [0,8192)
#define PROC_TILE(X, cvec)                                                     \
  {                                                                            \
    _Pragma("unroll") for (int kb = 0; kb < 4; ++kb) {                         \
      float xv[8] = {X[2 * kb].x,     X[2 * kb].y,     X[2 * kb].z,            \
                     X[2 * kb].w,     X[2 * kb + 1].x, X[2 * kb + 1].y,        \
                     X[2 * kb + 1].z, X[2 * kb + 1].w};                        \
      bf16x8 xh;                                                               \
      _Pragma("unroll") for (int j = 0; j < 8; ++j) xh[j] = (short)f2bf(xv[j]); \
      bf16x8 wh = *(const bf16x8*)(smem + kb * 1024 + lane * 16);              \
      bf16x8 wl = *(const bf16x8*)(smem + 4096 + kb * 1024 + lane * 16);       \
      cvec = __builtin_amdgcn_mfma_f32_16x16x32_bf16(xh, wh, cvec, 0, 0, 0);   \
      cvec = __builtin_amdgcn_mfma_f32_16x16x32_bf16(xh, wl, cvec, 0, 0, 0);   \
    }                                                                          \
  }

  // lanes m<8 hold f_n[bg=kg*4+gg][h=m]; valid bg<8 -> kg<2 writes only
#define P1_SOFTMAX(tile, cvec)                                                 \
  if (m < 8 && kg < 2) {                                                       \
    float l[4], mx = -1e30f;                                                   \
    _Pragma("unroll") for (int gg = 0; gg < 4; ++gg) {                         \
      float v = lrelu_f(fs[gg] + (cvec)[gg]);                                  \
      l[gg] = v;                                                               \
      mx = fmaxf(mx, v);                                                       \
    }                                                                          \
    float s = 0.f;                                                             \
    _Pragma("unroll") for (int gg = 0; gg < 4; ++gg) {                         \
      l[gg] = __expf(l[gg] - mx);                                              \
      s += l[gg];                                                              \
    }                                                                          \
    float inv = 1.f / s;                                                       \
    _Pragma("unroll") for (int gg = 0; gg < 4; ++gg)                           \
      attw[(tile) * 64 + (kg * 4 + gg) * 8 + m] = l[gg] * inv;                 \
  }

  const int bl8 = m8 >> 2, g8 = m8 & 3;    // this lane's (b-within-pair, g)
  const float* base_n =
      neigh_vecs + (((size_t)(bid * 2 + bl8) * NNB) * GG + g8) * DIN;

  // ---- issue self + tile-A loads (in flight across the staging barrier) ----
  float4 XS[8], XA[8], XB[8], XC[8], XD[8], XE[8];
  LOAD_X(XS, self_vecs + ((size_t)bid * 8 + m8) * DIN)
  LOAD_X(XA, base_n + (size_t)w * (GG * DIN))

  // ---- stage P1 weights into LDS [0,8192) ----
  ((float4*)smem)[t]       = ((const float4*)P1Whi)[t];
  ((float4*)smem)[256 + t] = ((const float4*)P1Wlo)[t];
  __syncthreads();

  // ======== P1a: self tile ========
  f32x4 fs;
  {
    f32x4 c20 = {0.f, 0.f, 0.f, 0.f};
    PROC_TILE(XS, c20)
#pragma unroll
    for (int reg = 0; reg < 4; ++reg) fs[reg] = __shfl_xor(c20[reg], 8);
  }
  LOAD_X(XB, base_n + (size_t)(w + 4) * (GG * DIN))

  // ======== P1b: 5 n-tiles per wave (w, w+4, w+8, w+12, w+16) ========
  {
    f32x4 c = {0.f, 0.f, 0.f, 0.f};
    PROC_TILE(XA, c)
    LOAD_X(XC, base_n + (size_t)(w + 8) * (GG * DIN))
    P1_SOFTMAX(w, c)
  }
  {
    f32x4 c = {0.f, 0.f, 0.f, 0.f};
    PROC_TILE(XB, c)
    LOAD_X(XD, base_n + (size_t)(w + 12) * (GG * DIN))
    P1_SOFTMAX(w + 4, c)
  }
  {
    f32x4 c = {0.f, 0.f, 0.f, 0.f};
    PROC_TILE(XC, c)
    LOAD_X(XE, base_n + (size_t)(w + 16) * (GG * DIN))
    P1_SOFTMAX(w + 8, c)
  }
  {
    f32x4 c = {0.f, 0.f, 0.f, 0.f};
    PROC_TILE(XD, c)
    P1_SOFTMAX(w + 12, c)
  }
  {
    f32x4 c = {0.f, 0.f, 0.f, 0.f};
    PROC_TILE(XE, c)
    P1_SOFTMAX(w + 16, c)
  }
  __syncthreads();   // att complete; wf staging dead -> agg region free

  // ======== P3: dual-bg. wave w -> bg {2w, 2w+1}; lane: ih=lane>>5 ========
  {
    const int ih = lane >> 5;
    const int bg = 2 * w + ih;
    const int g0 = (2 * w) & 3;            // w even-> g0=0, w odd-> g0=2 (same b)
    const float* nb2 =
        neigh_vecs + (((size_t)(bid * 2 + (w >> 1)) * NNB) * GG + g0) * DIN;
    const int dl = 4 * (lane & 31);
    float acc[8][4];
#pragma unroll
    for (int h = 0; h < 8; ++h)
#pragma unroll
      for (int d = 0; d < 4; ++d) acc[h][d] = 0.f;
#pragma unroll
    for (int n = 0; n < NNB; ++n) {
      float4 x4 = *(const float4*)&nb2[(size_t)n * GG * DIN + 4 * lane];
      f32x4 a0 = *(const f32x4*)&attw[n * 64 + bg * 8];
      f32x4 a1 = *(const f32x4*)&attw[n * 64 + bg * 8 + 4];
#pragma unroll
      for (int h = 0; h < 4; ++h) {
        acc[h][0] = fmaf(a0[h], x4.x, acc[h][0]);
        acc[h][1] = fmaf(a0[h], x4.y, acc[h][1]);
        acc[h][2] = fmaf(a0[h], x4.z, acc[h][2]);
        acc[h][3] = fmaf(a0[h], x4.w, acc[h][3]);
        acc[h + 4][0] = fmaf(a1[h], x4.x, acc[h + 4][0]);
        acc[h + 4][1] = fmaf(a1[h], x4.y, acc[h + 4][1]);
        acc[h + 4][2] = fmaf(a1[h], x4.z, acc[h + 4][2]);
        acc[h + 4][3] = fmaf(a1[h], x4.w, acc[h + 4][3]);
      }
    }
    const int swz = bg << 4;               // bg < 8
#pragma unroll
    for (int h = 0; h < 8; ++h) {
      uint2 pk;
      pk.x = (unsigned)f2bf(acc[h][0]) | ((unsigned)f2bf(acc[h][1]) << 16);
      pk.y = (unsigned)f2bf(acc[h][2]) | ((unsigned)f2bf(acc[h][3]) << 16);
      *(uint2*)(aggb + ((bg * 2048 + h * 256 + 2 * dl) ^ swz)) = pk;
    }
  }
  __syncthreads();   // agg complete; att dead -> hb reuse

  // ======== phase B: wave w -> heads {2w, 2w+1}; h stored bf16 ========
#pragma unroll
  for (int hi_ = 0; hi_ < 2; ++hi_) {
    const int hh = 2 * w + hi_;
    const int aswz = m8 << 4;
    bf16x8 a[4];
#pragma unroll
    for (int kb = 0; kb < 4; ++kb)
      a[kb] = *(const bf16x8*)(aggb + ((m8 * 2048 + hh * 256 + kb * 64 + kg * 16) ^ aswz));
#pragma unroll
    for (int nt = 0; nt < 4; ++nt) {
      f32x4 c = {0.f, 0.f, 0.f, 0.f};
#pragma unroll
      for (int kb = 0; kb < 4; ++kb) {
        const int fi = (((hh * 4 + nt) * 4 + kb) * 64 + lane) * 8;
        bf16x8 bh = *(const bf16x8*)(WBhi + fi);
        bf16x8 bl_ = *(const bf16x8*)(WBlo + fi);
        c = __builtin_amdgcn_mfma_f32_16x16x32_bf16(a[kb], bh, c, 0, 0, 0);
        c = __builtin_amdgcn_mfma_f32_16x16x32_bf16(a[kb], bl_, c, 0, 0, 0);
      }
      if (kg < 2) {                         // valid D rows 0..7 only
        const int k = hh * 64 + nt * 16 + m;
#pragma unroll
        for (int reg = 0; reg < 4; ++reg) {
          int row = kg * 4 + reg;
          int byte = (row * 1024 + k * 2) ^ (row << 4);
          *(unsigned short*)(hb + byte) = f2bf(lrelu_f(c[reg]));
        }
      }
    }
  }
  __syncthreads();

  // ======== phase C: wave w -> nt = w (all waves active) ========
  {
    const int nt = w;
    f32x4 acc = {0.f, 0.f, 0.f, 0.f};
    for (int kb = 0; kb < 16; ++kb) {
      int byte = (m8 * 1024 + (kb * 32 + kg * 8) * 2) ^ (m8 << 4);
      bf16x8 ah = *(const bf16x8*)(hb + byte);
      const int fi = ((nt * 16 + kb) * 64 + lane) * 8;
      bf16x8 bh = *(const bf16x8*)(WOhi + fi);
      bf16x8 bl_ = *(const bf16x8*)(WOlo + fi);
      acc = __builtin_amdgcn_mfma_f32_16x16x32_bf16(ah, bh, acc, 0, 0, 0);
      acc = __builtin_amdgcn_mfma_f32_16x16x32_bf16(ah, bl_, acc, 0, 0, 0);
    }
    if (kg < 2) {                           // valid rows 0..7
      const size_t rbase = (size_t)bid * 8;
#pragma unroll
      for (int reg = 0; reg < 4; ++reg) {
        int row = kg * 4 + reg;
        out[(rbase + row) * EE + nt * 16 + m] = fmaxf(acc[reg], 0.f);
      }
    }
  }
#undef LOAD_X
#undef PROC_TILE
#undef P1_SOFTMAX
}

extern "C" void kernel_launch(void* const* d_in, const int* in_sizes, int n_in,
                              void* d_out, int out_size, void* d_ws, size_t ws_size,
                              hipStream_t stream) {
  (void)in_sizes; (void)n_in; (void)out_size; (void)ws_size;
  const float* self_vecs  = (const float*)d_in[0];
  const float* neigh_vecs = (const float*)d_in[1];
  const float* W_heads    = (const float*)d_in[2];
  const float* a_self     = (const float*)d_in[3];
  const float* a_neigh    = (const float*)d_in[4];
  const float* W_out      = (const float*)d_in[5];
  float* out              = (float*)d_out;

  char* ws = (char*)d_ws;
  unsigned short* P1Whi = (unsigned short*)ws;                    // 4 KB
  unsigned short* P1Wlo = (unsigned short*)(ws + 4096);           // 4 KB
  unsigned short* WBhi  = (unsigned short*)(ws + 8192);           // 128 KB
  unsigned short* WBlo  = (unsigned short*)(ws + 8192 + 131072);
  unsigned short* WOhi  = (unsigned short*)(ws + 8192 + 262144);  // 64 KB
  unsigned short* WOlo  = (unsigned short*)(ws + 8192 + 262144 + 65536);

  prep_kernel<<<(2048 + 65536 + 32768) / 256, 256, 0, stream>>>(
      W_heads, a_self, a_neigh, W_out, P1Whi, P1Wlo, WBhi, WBlo, WOhi, WOlo);

  fused_kernel<<<BB / 2, 256, 0, stream>>>(
      self_vecs, neigh_vecs, P1Whi, P1Wlo, WBhi, WBlo, WOhi, WOlo, out);
}